// Round 3
// baseline (135.017 us; speedup 1.0000x reference)
//
#include <hip/hip_runtime.h>
#include <math.h>

#define NC 14        // classes / centroids
#define BB 32        // batch
#define NN 16384     // subsampled points per batch
#define PP 4096      // origin points per batch

// ws layout (floats):
//   [0]               arrival counter (as unsigned int)
//   [16 .. 16+32)     chamfer partial per batch
//   [64 .. 64+512)    distance partial per block
//   [640 .. 640+1344) centroids [B][C][3]
#define WS_COUNTER 0
#define WS_CHAMFER 16
#define WS_DIST    64
#define WS_CENT    640
#define NBLK_B     (BB * (NN / 1024))   // 512

// Kernel A: per-batch centroids (register-private predicated accumulation),
// fused chamfer l1/l2 + separation -> ws slot. Also zeroes the arrival counter
// (stream-ordered before kernel B).
__global__ void centroids_chamfer_kernel(const float* __restrict__ origin, // [B,9,P]
                                         const int*   __restrict__ target, // [B,P]
                                         const float* __restrict__ cpred,  // [B,3,C]
                                         float* __restrict__ ws) {
    const int b    = blockIdx.x;
    const int tid  = threadIdx.x;
    const int lane = tid & 63;
    const int wave = tid >> 6;

    if (b == 0 && tid == 0) ((unsigned int*)ws)[WS_COUNTER] = 0u;

    float sx[NC], sy[NC], sz[NC], sc[NC];
    #pragma unroll
    for (int c = 0; c < NC; ++c) { sx[c] = sy[c] = sz[c] = sc[c] = 0.f; }

    const float* ob = origin + (size_t)b * 9 * PP;
    const int*   tb = target + (size_t)b * PP;

    // 4 points per thread via vector loads (PP=4096, 256 threads)
    const int p0 = tid * 4;
    #pragma unroll
    for (int it = 0; it < PP / 1024; ++it) {  // 4 iterations
        const int p = p0 + it * 1024;
        const int4   tv = *(const int4*)&tb[p];
        const float4 xv = *(const float4*)&ob[p];
        const float4 yv = *(const float4*)&ob[PP + p];
        const float4 zv = *(const float4*)&ob[2 * PP + p];
        const int   ts[4] = {tv.x, tv.y, tv.z, tv.w};
        const float xs[4] = {xv.x, xv.y, xv.z, xv.w};
        const float ys[4] = {yv.x, yv.y, yv.z, yv.w};
        const float zs[4] = {zv.x, zv.y, zv.z, zv.w};
        #pragma unroll
        for (int k = 0; k < 4; ++k) {
            #pragma unroll
            for (int c = 0; c < NC; ++c) {
                float m = (ts[k] == c) ? 1.f : 0.f;
                sx[c] = fmaf(m, xs[k], sx[c]);
                sy[c] = fmaf(m, ys[k], sy[c]);
                sz[c] = fmaf(m, zs[k], sz[c]);
                sc[c] += m;
            }
        }
    }

    // wave-level shuffle reduction (64 lanes)
    #pragma unroll
    for (int c = 0; c < NC; ++c) {
        #pragma unroll
        for (int o = 32; o > 0; o >>= 1) {
            sx[c] += __shfl_down(sx[c], o);
            sy[c] += __shfl_down(sy[c], o);
            sz[c] += __shfl_down(sz[c], o);
            sc[c] += __shfl_down(sc[c], o);
        }
    }

    __shared__ float s_part[4][NC][4];
    if (lane == 0) {
        #pragma unroll
        for (int c = 0; c < NC; ++c) {
            s_part[wave][c][0] = sx[c];
            s_part[wave][c][1] = sy[c];
            s_part[wave][c][2] = sz[c];
            s_part[wave][c][3] = sc[c];
        }
    }
    __syncthreads();

    __shared__ float s_cent[NC][3];
    if (tid < NC * 3) {
        int c = tid / 3, d = tid % 3;
        float s = s_part[0][c][d] + s_part[1][c][d] + s_part[2][c][d] + s_part[3][c][d];
        float n = s_part[0][c][3] + s_part[1][c][3] + s_part[2][c][3] + s_part[3][c][3];
        float v = s / fmaxf(n, 1.f);
        s_cent[c][d] = v;
        ws[WS_CENT + (size_t)b * NC * 3 + tid] = v;
    }
    __syncthreads();

    // D[cp][c] = ||pred[b,cp] - cent_gt[b,c]||^2  (pred from [B,3,C] layout)
    __shared__ float s_D[NC][NC];
    if (tid < NC * NC) {
        int cp = tid / NC, c = tid % NC;
        float dx = cpred[(size_t)b * 3 * NC + 0 * NC + cp] - s_cent[c][0];
        float dy = cpred[(size_t)b * 3 * NC + 1 * NC + cp] - s_cent[c][1];
        float dz = cpred[(size_t)b * 3 * NC + 2 * NC + cp] - s_cent[c][2];
        s_D[cp][c] = dx * dx + dy * dy + dz * dz;
    }
    __syncthreads();

    __shared__ float s_contrib[NC];
    if (tid < NC) {
        // l1: min over cp of D[cp][tid]
        float mn = s_D[0][tid];
        #pragma unroll
        for (int cp = 1; cp < NC; ++cp) mn = fminf(mn, s_D[cp][tid]);

        // l2 + separation for row cp = tid: two smallest of sqrt(D[tid][c])
        float m1 = 1e30f, m2 = 1e30f;
        #pragma unroll
        for (int c = 0; c < NC; ++c) {
            float d = sqrtf(s_D[tid][c]);
            if (d < m1) { m2 = m1; m1 = d; }
            else if (d < m2) { m2 = d; }
        }
        s_contrib[tid] = mn + m1 * m1 + 0.1f * (m1 / m2);
    }
    __syncthreads();
    if (tid == 0) {
        float s = 0.f;
        #pragma unroll
        for (int c = 0; c < NC; ++c) s += s_contrib[c];
        ws[WS_CHAMFER + b] = s;   // deterministic per-batch slot
    }
}

// Kernel B: 4 points/thread via float4, nearest-centroid dist + smooth-L1,
// block reduce -> per-block slot; last-arriving block reduces all slots -> out.
__global__ void distance_loss_kernel(const float* __restrict__ disp, // [B,N]
                                     const float* __restrict__ sub,  // [B,3,N]
                                     float* __restrict__ ws,
                                     float* __restrict__ out) {
    const int blocksPerBatch = NN / 1024;          // 16
    const int b  = blockIdx.x / blocksPerBatch;
    const int n0 = (blockIdx.x % blocksPerBatch) * 1024 + threadIdx.x * 4;

    __shared__ float s_cent[NC * 3];
    if (threadIdx.x < NC * 3)
        s_cent[threadIdx.x] = ws[WS_CENT + (size_t)b * NC * 3 + threadIdx.x];
    __syncthreads();

    const float4 xv = *(const float4*)&sub[((size_t)b * 3 + 0) * NN + n0];
    const float4 yv = *(const float4*)&sub[((size_t)b * 3 + 1) * NN + n0];
    const float4 zv = *(const float4*)&sub[((size_t)b * 3 + 2) * NN + n0];
    const float4 dv = *(const float4*)&disp[(size_t)b * NN + n0];

    const float xs[4] = {xv.x, xv.y, xv.z, xv.w};
    const float ys[4] = {yv.x, yv.y, yv.z, yv.w};
    const float zs[4] = {zv.x, zv.y, zv.z, zv.w};
    const float ds[4] = {dv.x, dv.y, dv.z, dv.w};

    float sm = 0.f;
    #pragma unroll
    for (int k = 0; k < 4; ++k) {
        float mn = 1e30f;
        #pragma unroll
        for (int c = 0; c < NC; ++c) {
            float dx = xs[k] - s_cent[c * 3 + 0];
            float dy = ys[k] - s_cent[c * 3 + 1];
            float dz = zs[k] - s_cent[c * 3 + 2];
            mn = fminf(mn, dx * dx + dy * dy + dz * dz);
        }
        float v  = ds[k] - sqrtf(mn);
        float av = fabsf(v);
        sm += (av < 1.f) ? 0.5f * v * v : (av - 0.5f);
    }

    #pragma unroll
    for (int o = 32; o > 0; o >>= 1) sm += __shfl_down(sm, o);

    __shared__ float s_part[4];
    const int wave = threadIdx.x >> 6;
    if ((threadIdx.x & 63) == 0) s_part[wave] = sm;
    __syncthreads();

    __shared__ unsigned int s_old;
    if (threadIdx.x == 0) {
        ws[WS_DIST + blockIdx.x] = s_part[0] + s_part[1] + s_part[2] + s_part[3];
        __threadfence();   // make slot visible device-wide before arrival
        s_old = atomicAdd((unsigned int*)ws + WS_COUNTER, 1u);
    }
    __syncthreads();

    if (s_old == NBLK_B - 1) {
        // last block: reduce 512 dist slots + 32 chamfer slots -> out
        __threadfence();
        float acc = 0.f;
        for (int i = threadIdx.x; i < NBLK_B; i += 256)
            acc += __hip_atomic_load(&ws[WS_DIST + i], __ATOMIC_RELAXED,
                                     __HIP_MEMORY_SCOPE_AGENT);
        if (threadIdx.x < BB)
            acc += __hip_atomic_load(&ws[WS_CHAMFER + threadIdx.x], __ATOMIC_RELAXED,
                                     __HIP_MEMORY_SCOPE_AGENT);
        #pragma unroll
        for (int o = 32; o > 0; o >>= 1) acc += __shfl_down(acc, o);
        __shared__ float s_fin[4];
        if ((threadIdx.x & 63) == 0) s_fin[threadIdx.x >> 6] = acc;
        __syncthreads();
        if (threadIdx.x == 0)
            *out = s_fin[0] + s_fin[1] + s_fin[2] + s_fin[3];
    }
}

extern "C" void kernel_launch(void* const* d_in, const int* in_sizes, int n_in,
                              void* d_out, int out_size, void* d_ws, size_t ws_size,
                              hipStream_t stream) {
    const float* disp   = (const float*)d_in[0]; // [B,N]
    const float* sub    = (const float*)d_in[1]; // [B,3,N]
    const float* cpred  = (const float*)d_in[2]; // [B,3,C]
    const float* origin = (const float*)d_in[3]; // [B,9,P]
    const int*   target = (const int*)d_in[4];   // [B,P]

    float* out = (float*)d_out;
    float* ws  = (float*)d_ws;

    centroids_chamfer_kernel<<<BB, 256, 0, stream>>>(origin, target, cpred, ws);
    distance_loss_kernel<<<NBLK_B, 256, 0, stream>>>(disp, sub, ws, out);
}

// Round 4
// 84.300 us; speedup vs baseline: 1.6016x; 1.6016x over previous
//
#include <hip/hip_runtime.h>
#include <math.h>

#define NC 14        // classes / centroids
#define BB 32        // batch
#define NN 16384     // subsampled points per batch
#define PP 4096      // origin points per batch

// ws layout (floats):
//   [0]               arrival counter (unsigned int)
//   [64 .. 64+512)    per-block partial (distance; +chamfer on first block/batch)
//   [640 .. 640+1344) centroids [B][C][3]
#define WS_COUNTER 0
#define WS_DIST    64
#define WS_CENT    640
#define BLK_PER_B  (NN / 1024)          // 16
#define NBLK_B     (BB * BLK_PER_B)     // 512

// Kernel A: one block per (batch, class). Each thread keeps just 4
// accumulators -> no spill. Block reduces and writes the centroid.
__global__ void centroids_kernel(const float* __restrict__ origin, // [B,9,P]
                                 const int*   __restrict__ target, // [B,P]
                                 float* __restrict__ ws) {
    const int b    = blockIdx.x / NC;
    const int c    = blockIdx.x % NC;
    const int tid  = threadIdx.x;
    const int lane = tid & 63;
    const int wave = tid >> 6;

    if (blockIdx.x == 0 && tid == 0) ((unsigned int*)ws)[WS_COUNTER] = 0u;

    const float* ob = origin + (size_t)b * 9 * PP;
    const int*   tb = target + (size_t)b * PP;

    float sx = 0.f, sy = 0.f, sz = 0.f, cnt = 0.f;
    const int p0 = tid * 4;
    #pragma unroll
    for (int it = 0; it < PP / 1024; ++it) {   // 4 iterations, 16 pts/thread
        const int p = p0 + it * 1024;
        const int4   tv = *(const int4*)&tb[p];
        const float4 xv = *(const float4*)&ob[p];
        const float4 yv = *(const float4*)&ob[PP + p];
        const float4 zv = *(const float4*)&ob[2 * PP + p];
        float m0 = (tv.x == c) ? 1.f : 0.f;
        float m1 = (tv.y == c) ? 1.f : 0.f;
        float m2 = (tv.z == c) ? 1.f : 0.f;
        float m3 = (tv.w == c) ? 1.f : 0.f;
        sx = fmaf(m0, xv.x, fmaf(m1, xv.y, fmaf(m2, xv.z, fmaf(m3, xv.w, sx))));
        sy = fmaf(m0, yv.x, fmaf(m1, yv.y, fmaf(m2, yv.z, fmaf(m3, yv.w, sy))));
        sz = fmaf(m0, zv.x, fmaf(m1, zv.y, fmaf(m2, zv.z, fmaf(m3, zv.w, sz))));
        cnt += m0 + m1 + m2 + m3;
    }

    #pragma unroll
    for (int o = 32; o > 0; o >>= 1) {
        sx  += __shfl_down(sx, o);
        sy  += __shfl_down(sy, o);
        sz  += __shfl_down(sz, o);
        cnt += __shfl_down(cnt, o);
    }

    __shared__ float s_part[4][4];
    if (lane == 0) {
        s_part[wave][0] = sx; s_part[wave][1] = sy;
        s_part[wave][2] = sz; s_part[wave][3] = cnt;
    }
    __syncthreads();

    if (tid == 0) {
        float X = s_part[0][0] + s_part[1][0] + s_part[2][0] + s_part[3][0];
        float Y = s_part[0][1] + s_part[1][1] + s_part[2][1] + s_part[3][1];
        float Z = s_part[0][2] + s_part[1][2] + s_part[2][2] + s_part[3][2];
        float n = fmaxf(s_part[0][3] + s_part[1][3] + s_part[2][3] + s_part[3][3], 1.f);
        const int base = WS_CENT + (b * NC + c) * 3;
        ws[base + 0] = X / n;
        ws[base + 1] = Y / n;
        ws[base + 2] = Z / n;
    }
}

// Kernel B: distance loss (4 pts/thread, float4); first block of each batch
// also computes chamfer l1/l2 + separation from the LDS centroids; per-block
// partial -> slot; last-arriving block reduces all 512 slots -> out.
__global__ void distance_loss_kernel(const float* __restrict__ disp,  // [B,N]
                                     const float* __restrict__ sub,   // [B,3,N]
                                     const float* __restrict__ cpred, // [B,3,C]
                                     float* __restrict__ ws,
                                     float* __restrict__ out) {
    const int b  = blockIdx.x / BLK_PER_B;
    const int j  = blockIdx.x % BLK_PER_B;
    const int n0 = j * 1024 + threadIdx.x * 4;

    __shared__ float s_cent[NC * 3];
    if (threadIdx.x < NC * 3)
        s_cent[threadIdx.x] = ws[WS_CENT + (size_t)b * NC * 3 + threadIdx.x];
    __syncthreads();

    const float4 xv = *(const float4*)&sub[((size_t)b * 3 + 0) * NN + n0];
    const float4 yv = *(const float4*)&sub[((size_t)b * 3 + 1) * NN + n0];
    const float4 zv = *(const float4*)&sub[((size_t)b * 3 + 2) * NN + n0];
    const float4 dv = *(const float4*)&disp[(size_t)b * NN + n0];

    const float xs[4] = {xv.x, xv.y, xv.z, xv.w};
    const float ys[4] = {yv.x, yv.y, yv.z, yv.w};
    const float zs[4] = {zv.x, zv.y, zv.z, zv.w};
    const float ds[4] = {dv.x, dv.y, dv.z, dv.w};

    float sm = 0.f;
    #pragma unroll
    for (int k = 0; k < 4; ++k) {
        float mn = 1e30f;
        #pragma unroll
        for (int c = 0; c < NC; ++c) {
            float dx = xs[k] - s_cent[c * 3 + 0];
            float dy = ys[k] - s_cent[c * 3 + 1];
            float dz = zs[k] - s_cent[c * 3 + 2];
            mn = fminf(mn, dx * dx + dy * dy + dz * dz);
        }
        float v  = ds[k] - sqrtf(mn);
        float av = fabsf(v);
        sm += (av < 1.f) ? 0.5f * v * v : (av - 0.5f);
    }

    #pragma unroll
    for (int o = 32; o > 0; o >>= 1) sm += __shfl_down(sm, o);

    __shared__ float s_part[4];
    const int wave = threadIdx.x >> 6;
    if ((threadIdx.x & 63) == 0) s_part[wave] = sm;

    // chamfer + separation: only on the first block of each batch
    __shared__ float s_chamfer;
    if (j == 0) {
        __shared__ float s_D[NC][NC];
        if (threadIdx.x < NC * NC) {
            int cp = threadIdx.x / NC, c = threadIdx.x % NC;
            float dx = cpred[(size_t)b * 3 * NC + 0 * NC + cp] - s_cent[c * 3 + 0];
            float dy = cpred[(size_t)b * 3 * NC + 1 * NC + cp] - s_cent[c * 3 + 1];
            float dz = cpred[(size_t)b * 3 * NC + 2 * NC + cp] - s_cent[c * 3 + 2];
            s_D[cp][c] = dx * dx + dy * dy + dz * dz;
        }
        __syncthreads();
        __shared__ float s_contrib[NC];
        if (threadIdx.x < NC) {
            float mn = s_D[0][threadIdx.x];          // l1: min over cp
            #pragma unroll
            for (int cp = 1; cp < NC; ++cp) mn = fminf(mn, s_D[cp][threadIdx.x]);
            float m1 = 1e30f, m2 = 1e30f;            // row cp=tid: two smallest dists
            #pragma unroll
            for (int c = 0; c < NC; ++c) {
                float d = sqrtf(s_D[threadIdx.x][c]);
                if (d < m1) { m2 = m1; m1 = d; }
                else if (d < m2) { m2 = d; }
            }
            s_contrib[threadIdx.x] = mn + m1 * m1 + 0.1f * (m1 / m2);
        }
        __syncthreads();
        if (threadIdx.x == 0) {
            float s = 0.f;
            #pragma unroll
            for (int c = 0; c < NC; ++c) s += s_contrib[c];
            s_chamfer = s;
        }
    } else if (threadIdx.x == 0) {
        s_chamfer = 0.f;
    }
    __syncthreads();

    __shared__ unsigned int s_old;
    if (threadIdx.x == 0) {
        ws[WS_DIST + blockIdx.x] =
            s_part[0] + s_part[1] + s_part[2] + s_part[3] + s_chamfer;
        __threadfence();
        s_old = atomicAdd((unsigned int*)ws + WS_COUNTER, 1u);
    }
    __syncthreads();

    if (s_old == NBLK_B - 1) {
        __threadfence();
        float acc = 0.f;
        for (int i = threadIdx.x; i < NBLK_B; i += 256)
            acc += __hip_atomic_load(&ws[WS_DIST + i], __ATOMIC_RELAXED,
                                     __HIP_MEMORY_SCOPE_AGENT);
        #pragma unroll
        for (int o = 32; o > 0; o >>= 1) acc += __shfl_down(acc, o);
        __shared__ float s_fin[4];
        if ((threadIdx.x & 63) == 0) s_fin[threadIdx.x >> 6] = acc;
        __syncthreads();
        if (threadIdx.x == 0)
            *out = s_fin[0] + s_fin[1] + s_fin[2] + s_fin[3];
    }
}

extern "C" void kernel_launch(void* const* d_in, const int* in_sizes, int n_in,
                              void* d_out, int out_size, void* d_ws, size_t ws_size,
                              hipStream_t stream) {
    const float* disp   = (const float*)d_in[0]; // [B,N]
    const float* sub    = (const float*)d_in[1]; // [B,3,N]
    const float* cpred  = (const float*)d_in[2]; // [B,3,C]
    const float* origin = (const float*)d_in[3]; // [B,9,P]
    const int*   target = (const int*)d_in[4];   // [B,P]

    float* out = (float*)d_out;
    float* ws  = (float*)d_ws;

    centroids_kernel<<<BB * NC, 256, 0, stream>>>(origin, target, ws);
    distance_loss_kernel<<<NBLK_B, 256, 0, stream>>>(disp, sub, cpred, ws, out);
}